// Round 1
// baseline (757.935 us; speedup 1.0000x reference)
//
#include <hip/hip_runtime.h>

#define NB 8
#define HH 64
#define WW 32
#define CC 64
#define P2N 1680   // 60*28 dense patches (input_2)
#define P1N 420    // 30*14 strided patches (input_1)
#define OUTC 28
#define P1C 14
#define KF 1600
#define NP2 (NB*P2N)   // 13440
#define NP1 (NB*P1N)   // 3360

// One wave per patch: mean and 1/std over the 1600-elem patch vector.
__global__ __launch_bounds__(256) void stats_kernel(
    const float* __restrict__ in1, const float* __restrict__ in2,
    float* __restrict__ meanArr, float* __restrict__ invstdArr)
{
    int gid = blockIdx.x * 4 + (threadIdx.x >> 6);
    int lane = threadIdx.x & 63;
    const float* src; int b, y, x;
    if (gid < NP2) {
        b = gid / P2N; int p = gid % P2N;
        y = p / OUTC; x = p % OUTC;
        src = in2;
    } else {
        int g = gid - NP2;
        b = g / P1N; int p = g % P1N;
        y = (p / P1C) * 2; x = (p % P1C) * 2;
        src = in1;
    }
    const float* base = src + (((b*HH + y)*WW + x)*CC) + lane;
    float s = 0.f, s2 = 0.f;
#pragma unroll
    for (int i = 0; i < 25; ++i) {
        int dy = i / 5, dx = i % 5;
        float v = base[(dy*WW + dx)*CC];
        s += v; s2 += v * v;
    }
#pragma unroll
    for (int off = 32; off; off >>= 1) {
        s  += __shfl_xor(s, off);
        s2 += __shfl_xor(s2, off);
    }
    if (lane == 0) {
        float m = s * (1.f / KF);
        float var = s2 * (1.f / KF) - m * m;
        meanArr[gid] = m;
        invstdArr[gid] = rsqrtf(var);
    }
}

#define BM 64
#define BN 64
#define LDP 68   // pad: bank step 4 between rows -> <=2-way conflicts (free)

__global__ __launch_bounds__(256) void corr_kernel(
    const float* __restrict__ in1, const float* __restrict__ in2,
    const float* __restrict__ meanArr, const float* __restrict__ invstdArr,
    float* __restrict__ out)
{
    __shared__ float As[BM][LDP];
    __shared__ float Bs[BN][LDP];
    const int b  = blockIdx.z;
    const int m0 = blockIdx.y * BM;
    const int n0 = blockIdx.x * BN;
    const int t  = threadIdx.x;
    const int tx = t & 15, ty = t >> 4;

    // staging: thread t loads row (t>>2), 16 floats at col (t&3)*16
    const int lr = t >> 2;
    const int lc = (t & 3) * 16;

    int ma = m0 + lr; if (ma > P2N - 1) ma = P2N - 1;
    int y2 = ma / OUTC, x2 = ma % OUTC;
    const float* aBase = in2 + (((long)b*HH + y2)*WW + x2)*CC + lc;

    int nbi = n0 + lr; if (nbi > P1N - 1) nbi = P1N - 1;
    int y1 = (nbi / P1C) * 2, x1 = (nbi % P1C) * 2;
    const float* bBase = in1 + (((long)b*HH + y1)*WW + x1)*CC + lc;

    float acc[4][4] = {};

    for (int kk = 0; kk < 25; ++kk) {
        const int dy = kk / 5, dx = kk % 5;
        const int goff = (dy*WW + dx)*CC;
        float4 av[4], bv[4];
#pragma unroll
        for (int q = 0; q < 4; ++q) {
            av[q] = *(const float4*)(aBase + goff + q*4);
            bv[q] = *(const float4*)(bBase + goff + q*4);
        }
        __syncthreads();   // previous iteration's readers done
#pragma unroll
        for (int q = 0; q < 4; ++q) {
            *(float4*)&As[lr][lc + q*4] = av[q];
            *(float4*)&Bs[lr][lc + q*4] = bv[q];
        }
        __syncthreads();
#pragma unroll
        for (int k4 = 0; k4 < 16; ++k4) {
            float4 a[4], bb[4];
#pragma unroll
            for (int i = 0; i < 4; ++i) a[i]  = *(const float4*)&As[ty + 16*i][k4*4];
#pragma unroll
            for (int j = 0; j < 4; ++j) bb[j] = *(const float4*)&Bs[tx + 16*j][k4*4];
#pragma unroll
            for (int i = 0; i < 4; ++i)
#pragma unroll
                for (int j = 0; j < 4; ++j)
                    acc[i][j] += a[i].x*bb[j].x + a[i].y*bb[j].y
                               + a[i].z*bb[j].z + a[i].w*bb[j].w;
        }
    }

    // epilogue: (dot - K*m2*m1) * is2 * is1
    float m2v[4], is2v[4], m1v[4], is1v[4];
#pragma unroll
    for (int i = 0; i < 4; ++i) {
        int m = m0 + ty + 16*i; if (m > P2N - 1) m = P2N - 1;
        m2v[i]  = meanArr[b*P2N + m];
        is2v[i] = invstdArr[b*P2N + m];
    }
#pragma unroll
    for (int j = 0; j < 4; ++j) {
        int n = n0 + tx + 16*j; if (n > P1N - 1) n = P1N - 1;
        m1v[j]  = meanArr[NP2 + b*P1N + n];
        is1v[j] = invstdArr[NP2 + b*P1N + n];
    }
#pragma unroll
    for (int i = 0; i < 4; ++i) {
        int m = m0 + ty + 16*i;
        if (m >= P2N) continue;
#pragma unroll
        for (int j = 0; j < 4; ++j) {
            int n = n0 + tx + 16*j;
            if (n >= P1N) continue;
            float r = (acc[i][j] - (float)KF * m2v[i] * m1v[j]) * is2v[i] * is1v[j];
            out[(b*P2N + m)*P1N + n] = r;
        }
    }
}

extern "C" void kernel_launch(void* const* d_in, const int* in_sizes, int n_in,
                              void* d_out, int out_size, void* d_ws, size_t ws_size,
                              hipStream_t stream) {
    const float* in1 = (const float*)d_in[0];   // input_1 (strided patches)
    const float* in2 = (const float*)d_in[1];   // input_2 (dense patches)
    float* out = (float*)d_out;
    float* meanArr   = (float*)d_ws;
    float* invstdArr = meanArr + (NP2 + NP1);

    stats_kernel<<<(NP2 + NP1) / 4, 256, 0, stream>>>(in1, in2, meanArr, invstdArr);

    dim3 grid((P1N + BN - 1) / BN, (P2N + BM - 1) / BM, NB);
    corr_kernel<<<grid, 256, 0, stream>>>(in1, in2, meanArr, invstdArr, out);
}

// Round 2
// 65.703 us; speedup vs baseline: 11.5357x; 11.5357x over previous
//
#include <hip/hip_runtime.h>

typedef float f32x4 __attribute__((ext_vector_type(4)));
typedef short s16x8 __attribute__((ext_vector_type(8)));
typedef unsigned int u32;
typedef u32 u32x2 __attribute__((ext_vector_type(2)));
typedef u32 u32x4 __attribute__((ext_vector_type(4)));

#define NB 8
#define HH 64
#define WW 32
#define CC 64
#define P2N 1680   // 60*28 dense patches (input_2) = M
#define P1N 420    // 30*14 strided patches (input_1) = N
#define OUTC 28
#define P1C 14
#define KF 1600
#define NP2 (NB*P2N)
#define NP1 (NB*P1N)
#define NELEM (NB*HH*WW*CC)   // 1048576 elements per input

#define BM 128
#define BN 64

__device__ __forceinline__ u32 pack2_bf16(float x, float y) {
    u32 ux = __builtin_bit_cast(u32, x);
    u32 uy = __builtin_bit_cast(u32, y);
    ux = (ux + 0x7FFFu + ((ux >> 16) & 1u)) >> 16;
    uy = (uy + 0x7FFFu + ((uy >> 16) & 1u)) & 0xFFFF0000u;
    return (ux & 0xFFFFu) | uy;
}

// One wave per patch: mean and 1/std over the 1600-elem patch vector (exact fp32).
__global__ __launch_bounds__(256) void stats_kernel(
    const float* __restrict__ in1, const float* __restrict__ in2,
    float* __restrict__ meanArr, float* __restrict__ invstdArr)
{
    int gid = blockIdx.x * 4 + (threadIdx.x >> 6);
    int lane = threadIdx.x & 63;
    const float* src; int b, y, x;
    if (gid < NP2) {
        b = gid / P2N; int p = gid % P2N;
        y = p / OUTC; x = p % OUTC;
        src = in2;
    } else {
        int g = gid - NP2;
        b = g / P1N; int p = g % P1N;
        y = (p / P1C) * 2; x = (p % P1C) * 2;
        src = in1;
    }
    const float* base = src + (((b*HH + y)*WW + x)*CC) + lane;
    float s = 0.f, s2 = 0.f;
#pragma unroll
    for (int i = 0; i < 25; ++i) {
        int dy = i / 5, dx = i % 5;
        float v = base[(dy*WW + dx)*CC];
        s += v; s2 += v * v;
    }
#pragma unroll
    for (int off = 32; off; off >>= 1) {
        s  += __shfl_xor(s, off);
        s2 += __shfl_xor(s2, off);
    }
    if (lane == 0) {
        float m = s * (1.f / KF);
        float var = s2 * (1.f / KF) - m * m;
        meanArr[gid] = m;
        invstdArr[gid] = rsqrtf(var);
    }
}

// fp32 -> bf16 (RNE) conversion of both inputs into workspace.
__global__ __launch_bounds__(256) void cvt_kernel(
    const float* __restrict__ in1, const float* __restrict__ in2,
    u32* __restrict__ o1, u32* __restrict__ o2)
{
    int i = blockIdx.x * 256 + threadIdx.x;   // one float4 per thread
    if (i < NELEM/4) {
        f32x4 a = *(const f32x4*)(in1 + (size_t)i*4);
        f32x4 b = *(const f32x4*)(in2 + (size_t)i*4);
        u32x2 pa = { pack2_bf16(a.x, a.y), pack2_bf16(a.z, a.w) };
        u32x2 pb = { pack2_bf16(b.x, b.y), pack2_bf16(b.z, b.w) };
        ((u32x2*)o1)[i] = pa;
        ((u32x2*)o2)[i] = pb;
    }
}

// MFMA correlation GEMM. a_src = input_2 side (M=1680), b_src = input_1 side (N=420).
// BF16IN: operands already bf16 in workspace; else fp32 originals, cvt during staging.
template<bool BF16IN>
__global__ __launch_bounds__(256) void corr_mfma(
    const void* __restrict__ a_src, const void* __restrict__ b_src,
    const float* __restrict__ meanArr, const float* __restrict__ invstdArr,
    float* __restrict__ out)
{
    __shared__ short As[BM*64];   // 16 KB, XOR-swizzled rows of 128 B
    __shared__ short Bs[BN*64];   // 8 KB

    const int b  = blockIdx.z;
    const int m0 = blockIdx.y * BM;
    const int n0 = blockIdx.x * BN;
    const int t  = threadIdx.x;
    const int lane = t & 63;
    const int wid  = t >> 6;
    const int wm = wid >> 1, wn = wid & 1;          // 2x2 waves -> 64x32 each
    const int fr = lane & 15, fh = lane >> 4;

    // ---- staging geometry ----
    constexpr int NQA = BF16IN ? 4 : 8;   // A row-groups per thread
    constexpr int NQB = BF16IN ? 2 : 4;   // B row-groups per thread
    const int rsub   = BF16IN ? (t >> 3) : (t >> 4);        // row-in-group
    const int rstep  = BF16IN ? 32 : 16;                    // rows per group
    const int colElem = BF16IN ? ((t & 7) * 8) : ((t & 15) * 4); // elem offset in row
    const int colByte = BF16IN ? ((t & 7) * 16) : ((t & 15) * 8); // LDS byte offset
    const int swz = (rsub & 7) << 4;

    int aOff[NQA];
#pragma unroll
    for (int q = 0; q < NQA; ++q) {
        int ma = m0 + q*rstep + rsub; if (ma > P2N-1) ma = P2N-1;
        int y = ma / OUTC, x = ma % OUTC;
        aOff[q] = ((b*HH + y)*WW + x)*CC;
    }
    int bOff[NQB];
#pragma unroll
    for (int p = 0; p < NQB; ++p) {
        int nb = n0 + p*rstep + rsub; if (nb > P1N-1) nb = P1N-1;
        int y = (nb / P1C)*2, x = (nb % P1C)*2;
        bOff[p] = ((b*HH + y)*WW + x)*CC;
    }

    f32x4 acc[4][2];
#pragma unroll
    for (int i = 0; i < 4; ++i)
#pragma unroll
        for (int j = 0; j < 2; ++j) acc[i][j] = (f32x4){0.f,0.f,0.f,0.f};

    const float* aF = (const float*)a_src;
    const float* bF = (const float*)b_src;
    const short* aH = (const short*)a_src;
    const short* bH = (const short*)b_src;

    f32x4 avF[NQA], bvF[NQB];
    u32x4 avH[NQA], bvH[NQB];

    // prefetch chunk 0 (goff = 0)
    if constexpr (BF16IN) {
#pragma unroll
        for (int q = 0; q < NQA; ++q) avH[q] = *(const u32x4*)(aH + aOff[q] + colElem);
#pragma unroll
        for (int p = 0; p < NQB; ++p) bvH[p] = *(const u32x4*)(bH + bOff[p] + colElem);
    } else {
#pragma unroll
        for (int q = 0; q < NQA; ++q) avF[q] = *(const f32x4*)(aF + aOff[q] + colElem);
#pragma unroll
        for (int p = 0; p < NQB; ++p) bvF[p] = *(const f32x4*)(bF + bOff[p] + colElem);
    }

    char* AsB = (char*)As;
    char* BsB = (char*)Bs;

    for (int kk = 0; kk < 25; ++kk) {
        __syncthreads();   // readers of previous tile done
        // ---- write staged regs to LDS (swizzled) ----
        if constexpr (BF16IN) {
#pragma unroll
            for (int q = 0; q < NQA; ++q) {
                int row = q*rstep + rsub;
                *(u32x4*)(AsB + ((row*128 + colByte) ^ swz)) = avH[q];
            }
#pragma unroll
            for (int p = 0; p < NQB; ++p) {
                int row = p*rstep + rsub;
                *(u32x4*)(BsB + ((row*128 + colByte) ^ swz)) = bvH[p];
            }
        } else {
#pragma unroll
            for (int q = 0; q < NQA; ++q) {
                int row = q*rstep + rsub;
                u32x2 v = { pack2_bf16(avF[q].x, avF[q].y), pack2_bf16(avF[q].z, avF[q].w) };
                *(u32x2*)(AsB + ((row*128 + colByte) ^ swz)) = v;
            }
#pragma unroll
            for (int p = 0; p < NQB; ++p) {
                int row = p*rstep + rsub;
                u32x2 v = { pack2_bf16(bvF[p].x, bvF[p].y), pack2_bf16(bvF[p].z, bvF[p].w) };
                *(u32x2*)(BsB + ((row*128 + colByte) ^ swz)) = v;
            }
        }
        __syncthreads();

        // ---- prefetch next chunk (overlaps MFMA below) ----
        if (kk < 24) {
            int kn = kk + 1;
            int goff = ((kn/5)*WW + (kn%5))*CC + colElem;
            if constexpr (BF16IN) {
#pragma unroll
                for (int q = 0; q < NQA; ++q) avH[q] = *(const u32x4*)(aH + aOff[q] + goff);
#pragma unroll
                for (int p = 0; p < NQB; ++p) bvH[p] = *(const u32x4*)(bH + bOff[p] + goff);
            } else {
#pragma unroll
                for (int q = 0; q < NQA; ++q) avF[q] = *(const f32x4*)(aF + aOff[q] + goff);
#pragma unroll
                for (int p = 0; p < NQB; ++p) bvF[p] = *(const f32x4*)(bF + bOff[p] + goff);
            }
        }

        // ---- MFMA on current tile ----
#pragma unroll
        for (int step = 0; step < 2; ++step) {
            s16x8 af[4], bf[2];
#pragma unroll
            for (int i = 0; i < 4; ++i) {
                int row = wm*64 + i*16 + fr;
                af[i] = *(const s16x8*)(AsB + ((row*128 + step*64 + fh*16) ^ ((fr & 7) << 4)));
            }
#pragma unroll
            for (int j = 0; j < 2; ++j) {
                int row = wn*32 + j*16 + fr;
                bf[j] = *(const s16x8*)(BsB + ((row*128 + step*64 + fh*16) ^ ((fr & 7) << 4)));
            }
#pragma unroll
            for (int i = 0; i < 4; ++i)
#pragma unroll
                for (int j = 0; j < 2; ++j)
                    acc[i][j] = __builtin_amdgcn_mfma_f32_16x16x32_bf16(af[i], bf[j], acc[i][j], 0, 0, 0);
        }
    }

    // ---- epilogue: (dot - K*m2*m1) * is2 * is1 ----
    float m1v[2], is1v[2];
#pragma unroll
    for (int j = 0; j < 2; ++j) {
        int n = n0 + wn*32 + j*16 + fr;
        int nc = n > P1N-1 ? P1N-1 : n;
        m1v[j]  = meanArr[NP2 + b*P1N + nc];
        is1v[j] = invstdArr[NP2 + b*P1N + nc];
    }
#pragma unroll
    for (int i = 0; i < 4; ++i) {
#pragma unroll
        for (int r = 0; r < 4; ++r) {
            int m = m0 + wm*64 + i*16 + fh*4 + r;
            if (m >= P2N) continue;
            float m2  = meanArr[b*P2N + m];
            float is2 = invstdArr[b*P2N + m];
            size_t obase = ((size_t)b*P2N + m) * P1N;
#pragma unroll
            for (int j = 0; j < 2; ++j) {
                int n = n0 + wn*32 + j*16 + fr;
                if (n >= P1N) continue;
                out[obase + n] = (acc[i][j][r] - (float)KF * m2 * m1v[j]) * is2 * is1v[j];
            }
        }
    }
}

extern "C" void kernel_launch(void* const* d_in, const int* in_sizes, int n_in,
                              void* d_out, int out_size, void* d_ws, size_t ws_size,
                              hipStream_t stream) {
    const float* in1 = (const float*)d_in[0];   // strided patches -> N side
    const float* in2 = (const float*)d_in[1];   // dense patches   -> M side
    float* out = (float*)d_out;

    float* meanArr   = (float*)d_ws;
    float* invstdArr = meanArr + (NP2 + NP1);
    size_t statsBytes = (size_t)(NP2 + NP1) * 2 * sizeof(float);
    size_t off = (statsBytes + 255) & ~(size_t)255;
    short* b1 = (short*)((char*)d_ws + off);        // bf16 input_1, 2 MB
    short* b2 = b1 + NELEM;                          // bf16 input_2, 2 MB
    size_t need = off + (size_t)NELEM * 2 * sizeof(short);
    bool useBf16 = (ws_size >= need);

    stats_kernel<<<(NP2 + NP1) / 4, 256, 0, stream>>>(in1, in2, meanArr, invstdArr);

    dim3 grid((P1N + BN - 1) / BN, (P2N + BM - 1) / BM, NB);   // 7 x 14 x 8
    if (useBf16) {
        cvt_kernel<<<(NELEM/4 + 255)/256, 256, 0, stream>>>(in1, in2, (u32*)b1, (u32*)b2);
        corr_mfma<true><<<grid, 256, 0, stream>>>(b2, b1, meanArr, invstdArr, out);
    } else {
        corr_mfma<false><<<grid, 256, 0, stream>>>(in2, in1, meanArr, invstdArr, out);
    }
}

// Round 3
// 54.446 us; speedup vs baseline: 13.9209x; 1.2068x over previous
//
#include <hip/hip_runtime.h>

typedef float f32x4 __attribute__((ext_vector_type(4)));
typedef short s16x8 __attribute__((ext_vector_type(8)));
typedef unsigned int u32;
typedef u32 u32x2 __attribute__((ext_vector_type(2)));
typedef u32 u32x4 __attribute__((ext_vector_type(4)));

#define NB 8
#define HH 64
#define WW 32
#define CC 64
#define P2N 1680   // dense patches (input_2) = M
#define P1N 420    // strided patches (input_1) = N
#define OUTC 28
#define P1C 14
#define KF 1600
#define NP2 (NB*P2N)
#define NP1 (NB*P1N)
#define NELEM (NB*HH*WW*CC)

#define BM 128
#define BN 128

__device__ __forceinline__ u32 pack2_bf16(float x, float y) {
    u32 ux = __builtin_bit_cast(u32, x);
    u32 uy = __builtin_bit_cast(u32, y);
    ux = (ux + 0x7FFFu + ((ux >> 16) & 1u)) >> 16;
    uy = (uy + 0x7FFFu + ((uy >> 16) & 1u)) & 0xFFFF0000u;
    return (ux & 0xFFFFu) | uy;
}

// One wave per patch: mean and 1/std over the 1600-elem patch vector (exact fp32).
__global__ __launch_bounds__(256) void stats_kernel(
    const float* __restrict__ in1, const float* __restrict__ in2,
    float* __restrict__ meanArr, float* __restrict__ invstdArr)
{
    int gid = blockIdx.x * 4 + (threadIdx.x >> 6);
    int lane = threadIdx.x & 63;
    const float* src; int b, y, x;
    if (gid < NP2) {
        b = gid / P2N; int p = gid % P2N;
        y = p / OUTC; x = p % OUTC;
        src = in2;
    } else {
        int g = gid - NP2;
        b = g / P1N; int p = g % P1N;
        y = (p / P1C) * 2; x = (p % P1C) * 2;
        src = in1;
    }
    const float* base = src + (((b*HH + y)*WW + x)*CC) + lane;
    float s = 0.f, s2 = 0.f;
#pragma unroll
    for (int i = 0; i < 25; ++i) {
        int dy = i / 5, dx = i % 5;
        float v = base[(dy*WW + dx)*CC];
        s += v; s2 += v * v;
    }
#pragma unroll
    for (int off = 32; off; off >>= 1) {
        s  += __shfl_xor(s, off);
        s2 += __shfl_xor(s2, off);
    }
    if (lane == 0) {
        float m = s * (1.f / KF);
        float var = s2 * (1.f / KF) - m * m;
        meanArr[gid] = m;
        invstdArr[gid] = rsqrtf(var);
    }
}

// fp32 -> bf16 (RNE) conversion of both inputs into workspace.
__global__ __launch_bounds__(256) void cvt_kernel(
    const float* __restrict__ in1, const float* __restrict__ in2,
    u32* __restrict__ o1, u32* __restrict__ o2)
{
    int i = blockIdx.x * 256 + threadIdx.x;
    if (i < NELEM/4) {
        f32x4 a = *(const f32x4*)(in1 + (size_t)i*4);
        f32x4 b = *(const f32x4*)(in2 + (size_t)i*4);
        u32x2 pa = { pack2_bf16(a.x, a.y), pack2_bf16(a.z, a.w) };
        u32x2 pb = { pack2_bf16(b.x, b.y), pack2_bf16(b.z, b.w) };
        ((u32x2*)o1)[i] = pa;
        ((u32x2*)o2)[i] = pb;
    }
}

// MFMA correlation GEMM. 128x128 block, 4 waves (2x2) of 64x64 each.
// Double-buffered LDS, one barrier per K-chunk (64 elems = one (dy,dx) slice).
template<bool BF16IN>
__global__ __launch_bounds__(256) void corr_mfma(
    const void* __restrict__ a_src, const void* __restrict__ b_src,
    const float* __restrict__ meanArr, const float* __restrict__ invstdArr,
    float* __restrict__ out)
{
    __shared__ short As[2][BM*64];   // 2 x 16 KB
    __shared__ short Bs[2][BN*64];   // 2 x 16 KB

    const int b  = blockIdx.z;
    const int m0 = blockIdx.y * BM;
    const int n0 = blockIdx.x * BN;
    const int t  = threadIdx.x;
    const int lane = t & 63;
    const int wid  = t >> 6;
    const int wm = wid >> 1, wn = wid & 1;      // 2x2 waves -> 64x64 each
    const int fr = lane & 15, fh = lane >> 4;

    // staging: thread t handles rows rsub+32q (q=0..3), 16B-unit c16 within row
    const int rsub = t >> 3;           // 0..31
    const int c16  = t & 7;            // 0..7
    const int colElem = c16 * 8;       // bf16 elems
    const int swz = (rsub & 7) << 4;
    const int wByte = rsub*128 + c16*16;

    int aOff[4], bOff[4];
#pragma unroll
    for (int q = 0; q < 4; ++q) {
        int ma = m0 + rsub + 32*q; if (ma > P2N-1) ma = P2N-1;
        int y = ma / OUTC, x = ma % OUTC;
        aOff[q] = ((b*HH + y)*WW + x)*CC;
        int nb = n0 + rsub + 32*q; if (nb > P1N-1) nb = P1N-1;
        int yy = (nb / P1C)*2, xx = (nb % P1C)*2;
        bOff[q] = ((b*HH + yy)*WW + xx)*CC;
    }

    f32x4 acc[4][4];
#pragma unroll
    for (int i = 0; i < 4; ++i)
#pragma unroll
        for (int j = 0; j < 4; ++j) acc[i][j] = (f32x4){0.f,0.f,0.f,0.f};

    const float* aF = (const float*)a_src;
    const float* bF = (const float*)b_src;
    const short* aH = (const short*)a_src;
    const short* bH = (const short*)b_src;

    u32x4 avH[4], bvH[4];
    f32x4 avF[4][2], bvF[4][2];

    // prefetch chunk 0
    if constexpr (BF16IN) {
#pragma unroll
        for (int q = 0; q < 4; ++q) {
            avH[q] = *(const u32x4*)(aH + aOff[q] + colElem);
            bvH[q] = *(const u32x4*)(bH + bOff[q] + colElem);
        }
    } else {
#pragma unroll
        for (int q = 0; q < 4; ++q) {
            avF[q][0] = *(const f32x4*)(aF + aOff[q] + colElem);
            avF[q][1] = *(const f32x4*)(aF + aOff[q] + colElem + 4);
            bvF[q][0] = *(const f32x4*)(bF + bOff[q] + colElem);
            bvF[q][1] = *(const f32x4*)(bF + bOff[q] + colElem + 4);
        }
    }

    // write chunk 0 to LDS buffer 0
    {
        char* AsB = (char*)As[0];
        char* BsB = (char*)Bs[0];
        if constexpr (BF16IN) {
#pragma unroll
            for (int q = 0; q < 4; ++q) {
                *(u32x4*)(AsB + ((wByte + q*32*128) ^ swz)) = avH[q];
                *(u32x4*)(BsB + ((wByte + q*32*128) ^ swz)) = bvH[q];
            }
        } else {
#pragma unroll
            for (int q = 0; q < 4; ++q) {
                u32x4 va = { pack2_bf16(avF[q][0].x, avF[q][0].y), pack2_bf16(avF[q][0].z, avF[q][0].w),
                             pack2_bf16(avF[q][1].x, avF[q][1].y), pack2_bf16(avF[q][1].z, avF[q][1].w) };
                u32x4 vb = { pack2_bf16(bvF[q][0].x, bvF[q][0].y), pack2_bf16(bvF[q][0].z, bvF[q][0].w),
                             pack2_bf16(bvF[q][1].x, bvF[q][1].y), pack2_bf16(bvF[q][1].z, bvF[q][1].w) };
                *(u32x4*)(AsB + ((wByte + q*32*128) ^ swz)) = va;
                *(u32x4*)(BsB + ((wByte + q*32*128) ^ swz)) = vb;
            }
        }
    }

    for (int kk = 0; kk < 25; ++kk) {
        __syncthreads();   // LDS[kk&1] ready; MFMA(kk-1) readers of LDS[(kk+1)&1] done

        // ---- issue prefetch of chunk kk+1 (overlaps MFMA below) ----
        if (kk < 24) {
            int kn = kk + 1;
            int goff = ((kn/5)*WW + (kn%5))*CC + colElem;
            if constexpr (BF16IN) {
#pragma unroll
                for (int q = 0; q < 4; ++q) {
                    avH[q] = *(const u32x4*)(aH + aOff[q] + goff);
                    bvH[q] = *(const u32x4*)(bH + bOff[q] + goff);
                }
            } else {
#pragma unroll
                for (int q = 0; q < 4; ++q) {
                    avF[q][0] = *(const f32x4*)(aF + aOff[q] + goff);
                    avF[q][1] = *(const f32x4*)(aF + aOff[q] + goff + 4);
                    bvF[q][0] = *(const f32x4*)(bF + bOff[q] + goff);
                    bvF[q][1] = *(const f32x4*)(bF + bOff[q] + goff + 4);
                }
            }
        }

        // ---- MFMA on LDS[kk&1] ----
        {
            const char* AsB = (const char*)As[kk & 1];
            const char* BsB = (const char*)Bs[kk & 1];
            __builtin_amdgcn_s_setprio(1);
#pragma unroll
            for (int step = 0; step < 2; ++step) {
                s16x8 af[4], bf[4];
#pragma unroll
                for (int i = 0; i < 4; ++i) {
                    int row = wm*64 + i*16 + fr;
                    af[i] = *(const s16x8*)(AsB + ((row*128 + step*64 + fh*16) ^ ((fr & 7) << 4)));
                }
#pragma unroll
                for (int j = 0; j < 4; ++j) {
                    int row = wn*64 + j*16 + fr;
                    bf[j] = *(const s16x8*)(BsB + ((row*128 + step*64 + fh*16) ^ ((fr & 7) << 4)));
                }
#pragma unroll
                for (int i = 0; i < 4; ++i)
#pragma unroll
                    for (int j = 0; j < 4; ++j)
                        acc[i][j] = __builtin_amdgcn_mfma_f32_16x16x32_bf16(af[i], bf[j], acc[i][j], 0, 0, 0);
            }
            __builtin_amdgcn_s_setprio(0);
        }

        // ---- write chunk kk+1 into LDS[(kk+1)&1] ----
        if (kk < 24) {
            char* AsB = (char*)As[(kk + 1) & 1];
            char* BsB = (char*)Bs[(kk + 1) & 1];
            if constexpr (BF16IN) {
#pragma unroll
                for (int q = 0; q < 4; ++q) {
                    *(u32x4*)(AsB + ((wByte + q*32*128) ^ swz)) = avH[q];
                    *(u32x4*)(BsB + ((wByte + q*32*128) ^ swz)) = bvH[q];
                }
            } else {
#pragma unroll
                for (int q = 0; q < 4; ++q) {
                    u32x4 va = { pack2_bf16(avF[q][0].x, avF[q][0].y), pack2_bf16(avF[q][0].z, avF[q][0].w),
                                 pack2_bf16(avF[q][1].x, avF[q][1].y), pack2_bf16(avF[q][1].z, avF[q][1].w) };
                    u32x4 vb = { pack2_bf16(bvF[q][0].x, bvF[q][0].y), pack2_bf16(bvF[q][0].z, bvF[q][0].w),
                                 pack2_bf16(bvF[q][1].x, bvF[q][1].y), pack2_bf16(bvF[q][1].z, bvF[q][1].w) };
                    *(u32x4*)(AsB + ((wByte + q*32*128) ^ swz)) = va;
                    *(u32x4*)(BsB + ((wByte + q*32*128) ^ swz)) = vb;
                }
            }
        }
    }

    // ---- epilogue: (dot - K*m2*m1) * is2 * is1 ----
    float m1v[4], is1v[4];
#pragma unroll
    for (int j = 0; j < 4; ++j) {
        int n = n0 + wn*64 + j*16 + fr;
        int nc = n > P1N-1 ? P1N-1 : n;
        m1v[j]  = meanArr[NP2 + b*P1N + nc];
        is1v[j] = invstdArr[NP2 + b*P1N + nc];
    }
#pragma unroll
    for (int i = 0; i < 4; ++i) {
#pragma unroll
        for (int r = 0; r < 4; ++r) {
            int m = m0 + wm*64 + i*16 + fh*4 + r;
            if (m >= P2N) continue;
            float m2  = meanArr[b*P2N + m];
            float is2 = invstdArr[b*P2N + m];
            size_t obase = ((size_t)b*P2N + m) * P1N;
#pragma unroll
            for (int j = 0; j < 4; ++j) {
                int n = n0 + wn*64 + j*16 + fr;
                if (n >= P1N) continue;
                out[obase + n] = (acc[i][j][r] - (float)KF * m2 * m1v[j]) * is2 * is1v[j];
            }
        }
    }
}

extern "C" void kernel_launch(void* const* d_in, const int* in_sizes, int n_in,
                              void* d_out, int out_size, void* d_ws, size_t ws_size,
                              hipStream_t stream) {
    const float* in1 = (const float*)d_in[0];   // strided patches -> N side
    const float* in2 = (const float*)d_in[1];   // dense patches   -> M side
    float* out = (float*)d_out;

    float* meanArr   = (float*)d_ws;
    float* invstdArr = meanArr + (NP2 + NP1);
    size_t statsBytes = (size_t)(NP2 + NP1) * 2 * sizeof(float);
    size_t off = (statsBytes + 255) & ~(size_t)255;
    short* b1 = (short*)((char*)d_ws + off);
    short* b2 = b1 + NELEM;
    size_t need = off + (size_t)NELEM * 2 * sizeof(short);
    bool useBf16 = (ws_size >= need);

    stats_kernel<<<(NP2 + NP1) / 4, 256, 0, stream>>>(in1, in2, meanArr, invstdArr);

    dim3 grid((P1N + BN - 1) / BN, (P2N + BM - 1) / BM, NB);   // 4 x 14 x 8
    if (useBf16) {
        cvt_kernel<<<(NELEM/4 + 255)/256, 256, 0, stream>>>(in1, in2, (u32*)b1, (u32*)b2);
        corr_mfma<true><<<grid, 256, 0, stream>>>(b2, b1, meanArr, invstdArr, out);
    } else {
        corr_mfma<false><<<grid, 256, 0, stream>>>(in2, in1, meanArr, invstdArr, out);
    }
}

// Round 4
// 51.266 us; speedup vs baseline: 14.7845x; 1.0620x over previous
//
#include <hip/hip_runtime.h>

typedef float f32x4 __attribute__((ext_vector_type(4)));
typedef short s16x8 __attribute__((ext_vector_type(8)));
typedef unsigned int u32;
typedef u32 u32x2 __attribute__((ext_vector_type(2)));
typedef u32 u32x4 __attribute__((ext_vector_type(4)));

#define NB 8
#define HH 64
#define WW 32
#define CC 64
#define P2N 1680   // dense patches (input_2) = M
#define P1N 420    // strided patches (input_1) = N
#define OUTC 28
#define P1C 14
#define KF 1600
#define NP2 (NB*P2N)
#define NP1 (NB*P1N)
#define NELEM (NB*HH*WW*CC)   // 1048576
#define NPIX (NB*HH*WW)       // 16384

#define BM 128
#define BN 128

__device__ __forceinline__ u32 pack2_bf16(float x, float y) {
    u32 ux = __builtin_bit_cast(u32, x);
    u32 uy = __builtin_bit_cast(u32, y);
    ux = (ux + 0x7FFFu + ((ux >> 16) & 1u)) >> 16;
    uy = (uy + 0x7FFFu + ((uy >> 16) & 1u)) & 0xFFFF0000u;
    return (ux & 0xFFFFu) | uy;
}

// ---- fused fp32->bf16 convert + per-pixel channel sums (16 lanes = 1 pixel) ----
__global__ __launch_bounds__(256) void cvt_pix(
    const float* __restrict__ in1, const float* __restrict__ in2,
    u32* __restrict__ o1, u32* __restrict__ o2,
    float* __restrict__ pS1, float* __restrict__ pQ1,
    float* __restrict__ pS2, float* __restrict__ pQ2)
{
    int i = blockIdx.x * 256 + threadIdx.x;   // [0, NELEM/4)
    f32x4 a = *(const f32x4*)(in1 + (size_t)i*4);
    f32x4 c = *(const f32x4*)(in2 + (size_t)i*4);
    u32x2 pa = { pack2_bf16(a.x, a.y), pack2_bf16(a.z, a.w) };
    u32x2 pc = { pack2_bf16(c.x, c.y), pack2_bf16(c.z, c.w) };
    ((u32x2*)o1)[i] = pa;
    ((u32x2*)o2)[i] = pc;
    float s1 = a.x + a.y + a.z + a.w;
    float q1 = a.x*a.x + a.y*a.y + a.z*a.z + a.w*a.w;
    float s2 = c.x + c.y + c.z + c.w;
    float q2 = c.x*c.x + c.y*c.y + c.z*c.z + c.w*c.w;
#pragma unroll
    for (int off = 1; off < 16; off <<= 1) {
        s1 += __shfl_xor(s1, off); q1 += __shfl_xor(q1, off);
        s2 += __shfl_xor(s2, off); q2 += __shfl_xor(q2, off);
    }
    if ((threadIdx.x & 15) == 0) {
        int p = i >> 4;
        pS1[p] = s1; pQ1[p] = q1; pS2[p] = s2; pQ2[p] = q2;
    }
}

// ---- per-patch mean / invstd from pixel partial sums ----
__global__ __launch_bounds__(256) void pstats(
    const float* __restrict__ pS1, const float* __restrict__ pQ1,
    const float* __restrict__ pS2, const float* __restrict__ pQ2,
    float* __restrict__ meanArr, float* __restrict__ invstdArr)
{
    int gid = blockIdx.x * 256 + threadIdx.x;
    if (gid >= NP2 + NP1) return;
    const float *pS, *pQ; int b, y, x;
    if (gid < NP2) {
        b = gid / P2N; int p = gid % P2N;
        y = p / OUTC; x = p % OUTC;
        pS = pS2; pQ = pQ2;
    } else {
        int g = gid - NP2;
        b = g / P1N; int p = g % P1N;
        y = (p / P1C) * 2; x = (p % P1C) * 2;
        pS = pS1; pQ = pQ1;
    }
    int base = (b*HH + y)*WW + x;
    float s = 0.f, q = 0.f;
#pragma unroll
    for (int dy = 0; dy < 5; ++dy)
#pragma unroll
        for (int dx = 0; dx < 5; ++dx) {
            int pp = base + dy*WW + dx;
            s += pS[pp]; q += pQ[pp];
        }
    float m = s * (1.f / KF);
    meanArr[gid] = m;
    invstdArr[gid] = rsqrtf(q * (1.f / KF) - m * m);
}

// ---- fallback exact-fp32 stats (only used if ws too small) ----
__global__ __launch_bounds__(256) void stats_kernel(
    const float* __restrict__ in1, const float* __restrict__ in2,
    float* __restrict__ meanArr, float* __restrict__ invstdArr)
{
    int gid = blockIdx.x * 4 + (threadIdx.x >> 6);
    int lane = threadIdx.x & 63;
    const float* src; int b, y, x;
    if (gid < NP2) {
        b = gid / P2N; int p = gid % P2N;
        y = p / OUTC; x = p % OUTC;
        src = in2;
    } else {
        int g = gid - NP2;
        b = g / P1N; int p = g % P1N;
        y = (p / P1C) * 2; x = (p % P1C) * 2;
        src = in1;
    }
    const float* base = src + (((b*HH + y)*WW + x)*CC) + lane;
    float s = 0.f, s2 = 0.f;
#pragma unroll
    for (int i = 0; i < 25; ++i) {
        int dy = i / 5, dx = i % 5;
        float v = base[(dy*WW + dx)*CC];
        s += v; s2 += v * v;
    }
#pragma unroll
    for (int off = 32; off; off >>= 1) {
        s  += __shfl_xor(s, off);
        s2 += __shfl_xor(s2, off);
    }
    if (lane == 0) {
        float m = s * (1.f / KF);
        float var = s2 * (1.f / KF) - m * m;
        meanArr[gid] = m;
        invstdArr[gid] = rsqrtf(var);
    }
}

// ============ optimized bf16 MFMA correlation GEMM ============
// 128x128 block, 4 waves (2x2) of 64x64. Double-buffered LDS (manual layout:
// A0|B0|A1|B1 @ 16KB each), 1 barrier/chunk, 2-deep global prefetch,
// all LDS addresses = per-lane base VGPR + compile-time immediate.
__global__ __launch_bounds__(256) void corr_mfma_bf16(
    const short* __restrict__ aH, const short* __restrict__ bH,
    const float* __restrict__ meanArr, const float* __restrict__ invstdArr,
    float* __restrict__ out)
{
    __shared__ short lds[2*(BM+BN)*64];   // 64 KB
    char* L = (char*)lds;

    const int b  = blockIdx.z;
    const int m0 = blockIdx.y * BM;
    const int n0 = blockIdx.x * BN;
    const int t  = threadIdx.x;
    const int lane = t & 63;
    const int wid  = t >> 6;
    const int wm = wid >> 1, wn = wid & 1;      // 2x2 waves -> 64x64 each
    const int fr = lane & 15, fh = lane >> 4;

    // staging: thread t -> rows rsub+32q, 16B unit c16 within 128B row
    const int rsub = t >> 3;
    const int c16  = t & 7;
    // swizzle is confined to byte-bits 4..6 -> fold into base, immediates stay linear
    const int wBase = rsub*128 + ((c16*16) ^ ((rsub & 7) << 4));

    int aIdx[4], bIdx[4];   // element offsets incl. per-lane column
#pragma unroll
    for (int q = 0; q < 4; ++q) {
        int ma = m0 + rsub + 32*q; if (ma > P2N-1) ma = P2N-1;
        int y = ma / OUTC, x = ma % OUTC;
        aIdx[q] = ((b*HH + y)*WW + x)*CC + c16*8;
        int nb = n0 + rsub + 32*q; if (nb > P1N-1) nb = P1N-1;
        int yy = (nb / P1C)*2, xx = (nb % P1C)*2;
        bIdx[q] = ((b*HH + yy)*WW + xx)*CC + c16*8;
    }

    const int swz = (fr & 7) << 4;
    const int rA0 = (wm*64+fr)*128 + ((fh*16) ^ swz);
    const int rA1 = (wm*64+fr)*128 + ((64 + fh*16) ^ swz);
    const int rB0 = 16384 + (wn*64+fr)*128 + ((fh*16) ^ swz);
    const int rB1 = 16384 + (wn*64+fr)*128 + ((64 + fh*16) ^ swz);

    f32x4 acc[4][4];
#pragma unroll
    for (int i = 0; i < 4; ++i)
#pragma unroll
        for (int j = 0; j < 4; ++j) acc[i][j] = (f32x4){0.f,0.f,0.f,0.f};

    u32x4 av0[4], bv0[4], av1[4], bv1[4];   // two prefetch sets

#define GOFF(c) ((((c)/5)*WW + ((c)%5))*CC)
#define LOADG0(C) { _Pragma("unroll") for (int q = 0; q < 4; ++q) { \
        av0[q] = *(const u32x4*)(aH + aIdx[q] + GOFF(C)); \
        bv0[q] = *(const u32x4*)(bH + bIdx[q] + GOFF(C)); } }
#define LOADG1(C) { _Pragma("unroll") for (int q = 0; q < 4; ++q) { \
        av1[q] = *(const u32x4*)(aH + aIdx[q] + GOFF(C)); \
        bv1[q] = *(const u32x4*)(bH + bIdx[q] + GOFF(C)); } }
#define WRITE0(P) { _Pragma("unroll") for (int q = 0; q < 4; ++q) { \
        *(u32x4*)(L + wBase + q*4096 + (P)*32768)         = av0[q]; \
        *(u32x4*)(L + 16384 + wBase + q*4096 + (P)*32768) = bv0[q]; } }
#define WRITE1(P) { _Pragma("unroll") for (int q = 0; q < 4; ++q) { \
        *(u32x4*)(L + wBase + q*4096 + (P)*32768)         = av1[q]; \
        *(u32x4*)(L + 16384 + wBase + q*4096 + (P)*32768) = bv1[q]; } }

    // prologue: chunk0 -> set0 -> buf0; chunk1 -> set1 (in flight)
    LOADG0(0);
    LOADG1(1);
    WRITE0(0);

#pragma unroll
    for (int kk = 0; kk < 25; ++kk) {
        const int P = kk & 1;   // folds to literal under full unroll
        __syncthreads();        // buf[P] ready; prev readers of buf[1-P] done

        // issue loads of chunk kk+2 into set[P] (its data already in LDS)
        if (kk + 2 < 25) {
            if (P == 0) LOADG0(kk + 2) else LOADG1(kk + 2)
        }

        // MFMA on buf[P]
        __builtin_amdgcn_s_setprio(1);
#pragma unroll
        for (int s = 0; s < 2; ++s) {
            const int rAs = s ? rA1 : rA0;
            const int rBs = s ? rB1 : rB0;
            s16x8 af[4], bfr[4];
#pragma unroll
            for (int i = 0; i < 4; ++i)
                af[i] = *(const s16x8*)(L + rAs + i*2048 + P*32768);
#pragma unroll
            for (int j = 0; j < 4; ++j)
                bfr[j] = *(const s16x8*)(L + rBs + j*2048 + P*32768);
#pragma unroll
            for (int i = 0; i < 4; ++i)
#pragma unroll
                for (int j = 0; j < 4; ++j)
                    acc[i][j] = __builtin_amdgcn_mfma_f32_16x16x32_bf16(af[i], bfr[j], acc[i][j], 0, 0, 0);
        }
        __builtin_amdgcn_s_setprio(0);

        // write chunk kk+1 (set[1-P]) into buf[1-P]
        if (kk + 1 < 25) {
            if (P == 0) WRITE1(1) else WRITE0(0)
        }
    }

    // ---- epilogue: (dot - K*m2*m1) * is2 * is1 ----
    float m1v[4], is1v[4];
#pragma unroll
    for (int j = 0; j < 4; ++j) {
        int n = n0 + wn*64 + j*16 + fr;
        int nc = n > P1N-1 ? P1N-1 : n;
        m1v[j]  = meanArr[NP2 + b*P1N + nc];
        is1v[j] = invstdArr[NP2 + b*P1N + nc];
    }
#pragma unroll
    for (int i = 0; i < 4; ++i) {
#pragma unroll
        for (int r = 0; r < 4; ++r) {
            int m = m0 + wm*64 + i*16 + fh*4 + r;
            if (m >= P2N) continue;
            float m2  = meanArr[b*P2N + m];
            float is2 = invstdArr[b*P2N + m];
            size_t obase = ((size_t)b*P2N + m) * P1N;
#pragma unroll
            for (int j = 0; j < 4; ++j) {
                int n = n0 + wn*64 + j*16 + fr;
                if (n >= P1N) continue;
                out[obase + n] = (acc[i][j][r] - (float)KF * m2 * m1v[j]) * is2 * is1v[j];
            }
        }
    }
#undef GOFF
#undef LOADG0
#undef LOADG1
#undef WRITE0
#undef WRITE1
}

// ---- fallback fp32 corr (round-3 structure), used only if ws too small ----
__global__ __launch_bounds__(256) void corr_fp32(
    const float* __restrict__ aF, const float* __restrict__ bF,
    const float* __restrict__ meanArr, const float* __restrict__ invstdArr,
    float* __restrict__ out)
{
    __shared__ short As[2][BM*64];
    __shared__ short Bs[2][BN*64];
    const int b  = blockIdx.z;
    const int m0 = blockIdx.y * BM;
    const int n0 = blockIdx.x * BN;
    const int t  = threadIdx.x;
    const int lane = t & 63;
    const int wid  = t >> 6;
    const int wm = wid >> 1, wn = wid & 1;
    const int fr = lane & 15, fh = lane >> 4;
    const int rsub = t >> 3, c16 = t & 7;
    const int colElem = c16 * 8;
    const int swz = (rsub & 7) << 4;
    const int wByte = rsub*128 + c16*16;

    int aOff[4], bOff[4];
#pragma unroll
    for (int q = 0; q < 4; ++q) {
        int ma = m0 + rsub + 32*q; if (ma > P2N-1) ma = P2N-1;
        int y = ma / OUTC, x = ma % OUTC;
        aOff[q] = ((b*HH + y)*WW + x)*CC;
        int nb = n0 + rsub + 32*q; if (nb > P1N-1) nb = P1N-1;
        int yy = (nb / P1C)*2, xx = (nb % P1C)*2;
        bOff[q] = ((b*HH + yy)*WW + xx)*CC;
    }
    f32x4 acc[4][4];
#pragma unroll
    for (int i = 0; i < 4; ++i)
#pragma unroll
        for (int j = 0; j < 4; ++j) acc[i][j] = (f32x4){0.f,0.f,0.f,0.f};

    f32x4 avF[4][2], bvF[4][2];
#pragma unroll
    for (int q = 0; q < 4; ++q) {
        avF[q][0] = *(const f32x4*)(aF + aOff[q] + colElem);
        avF[q][1] = *(const f32x4*)(aF + aOff[q] + colElem + 4);
        bvF[q][0] = *(const f32x4*)(bF + bOff[q] + colElem);
        bvF[q][1] = *(const f32x4*)(bF + bOff[q] + colElem + 4);
    }
    {
        char* AsB = (char*)As[0]; char* BsB = (char*)Bs[0];
#pragma unroll
        for (int q = 0; q < 4; ++q) {
            u32x4 va = { pack2_bf16(avF[q][0].x, avF[q][0].y), pack2_bf16(avF[q][0].z, avF[q][0].w),
                         pack2_bf16(avF[q][1].x, avF[q][1].y), pack2_bf16(avF[q][1].z, avF[q][1].w) };
            u32x4 vb = { pack2_bf16(bvF[q][0].x, bvF[q][0].y), pack2_bf16(bvF[q][0].z, bvF[q][0].w),
                         pack2_bf16(bvF[q][1].x, bvF[q][1].y), pack2_bf16(bvF[q][1].z, bvF[q][1].w) };
            *(u32x4*)(AsB + ((wByte + q*4096) ^ swz)) = va;
            *(u32x4*)(BsB + ((wByte + q*4096) ^ swz)) = vb;
        }
    }
    for (int kk = 0; kk < 25; ++kk) {
        __syncthreads();
        if (kk < 24) {
            int kn = kk + 1;
            int goff = ((kn/5)*WW + (kn%5))*CC + colElem;
#pragma unroll
            for (int q = 0; q < 4; ++q) {
                avF[q][0] = *(const f32x4*)(aF + aOff[q] + goff);
                avF[q][1] = *(const f32x4*)(aF + aOff[q] + goff + 4);
                bvF[q][0] = *(const f32x4*)(bF + bOff[q] + goff);
                bvF[q][1] = *(const f32x4*)(bF + bOff[q] + goff + 4);
            }
        }
        {
            const char* AsB = (const char*)As[kk & 1];
            const char* BsB = (const char*)Bs[kk & 1];
#pragma unroll
            for (int step = 0; step < 2; ++step) {
                s16x8 af[4], bfr[4];
#pragma unroll
                for (int i = 0; i < 4; ++i) {
                    int row = wm*64 + i*16 + fr;
                    af[i] = *(const s16x8*)(AsB + ((row*128 + step*64 + fh*16) ^ ((fr & 7) << 4)));
                }
#pragma unroll
                for (int j = 0; j < 4; ++j) {
                    int row = wn*64 + j*16 + fr;
                    bfr[j] = *(const s16x8*)(BsB + ((row*128 + step*64 + fh*16) ^ ((fr & 7) << 4)));
                }
#pragma unroll
                for (int i = 0; i < 4; ++i)
#pragma unroll
                    for (int j = 0; j < 4; ++j)
                        acc[i][j] = __builtin_amdgcn_mfma_f32_16x16x32_bf16(af[i], bfr[j], acc[i][j], 0, 0, 0);
            }
        }
        if (kk < 24) {
            char* AsB = (char*)As[(kk + 1) & 1];
            char* BsB = (char*)Bs[(kk + 1) & 1];
#pragma unroll
            for (int q = 0; q < 4; ++q) {
                u32x4 va = { pack2_bf16(avF[q][0].x, avF[q][0].y), pack2_bf16(avF[q][0].z, avF[q][0].w),
                             pack2_bf16(avF[q][1].x, avF[q][1].y), pack2_bf16(avF[q][1].z, avF[q][1].w) };
                u32x4 vb = { pack2_bf16(bvF[q][0].x, bvF[q][0].y), pack2_bf16(bvF[q][0].z, bvF[q][0].w),
                             pack2_bf16(bvF[q][1].x, bvF[q][1].y), pack2_bf16(bvF[q][1].z, bvF[q][1].w) };
                *(u32x4*)(AsB + ((wByte + q*4096) ^ swz)) = va;
                *(u32x4*)(BsB + ((wByte + q*4096) ^ swz)) = vb;
            }
        }
    }
    float m1v[4], is1v[4];
#pragma unroll
    for (int j = 0; j < 4; ++j) {
        int n = n0 + wn*64 + j*16 + fr;
        int nc = n > P1N-1 ? P1N-1 : n;
        m1v[j]  = meanArr[NP2 + b*P1N + nc];
        is1v[j] = invstdArr[NP2 + b*P1N + nc];
    }
#pragma unroll
    for (int i = 0; i < 4; ++i) {
#pragma unroll
        for (int r = 0; r < 4; ++r) {
            int m = m0 + wm*64 + i*16 + fh*4 + r;
            if (m >= P2N) continue;
            float m2  = meanArr[b*P2N + m];
            float is2 = invstdArr[b*P2N + m];
            size_t obase = ((size_t)b*P2N + m) * P1N;
#pragma unroll
            for (int j = 0; j < 4; ++j) {
                int n = n0 + wn*64 + j*16 + fr;
                if (n >= P1N) continue;
                out[obase + n] = (acc[i][j][r] - (float)KF * m2 * m1v[j]) * is2 * is1v[j];
            }
        }
    }
}

extern "C" void kernel_launch(void* const* d_in, const int* in_sizes, int n_in,
                              void* d_out, int out_size, void* d_ws, size_t ws_size,
                              hipStream_t stream) {
    const float* in1 = (const float*)d_in[0];   // strided patches -> N side
    const float* in2 = (const float*)d_in[1];   // dense patches   -> M side
    float* out = (float*)d_out;

    float* meanArr   = (float*)d_ws;
    float* invstdArr = meanArr + (NP2 + NP1);
    float* pS1 = invstdArr + (NP2 + NP1);
    float* pQ1 = pS1 + NPIX;
    float* pS2 = pQ1 + NPIX;
    float* pQ2 = pS2 + NPIX;
    short* b1 = (short*)(pQ2 + NPIX);           // bf16 input_1 (16B-aligned offset)
    short* b2 = b1 + NELEM;                     // bf16 input_2
    size_t need = (size_t)((char*)(b2 + NELEM) - (char*)d_ws);
    bool useBf16 = (ws_size >= need);

    dim3 grid((P1N + BN - 1) / BN, (P2N + BM - 1) / BM, NB);   // 4 x 14 x 8

    if (useBf16) {
        cvt_pix<<<NELEM/4/256, 256, 0, stream>>>(in1, in2, (u32*)b1, (u32*)b2,
                                                 pS1, pQ1, pS2, pQ2);
        pstats<<<(NP2 + NP1 + 255)/256, 256, 0, stream>>>(pS1, pQ1, pS2, pQ2,
                                                          meanArr, invstdArr);
        corr_mfma_bf16<<<grid, 256, 0, stream>>>(b2, b1, meanArr, invstdArr, out);
    } else {
        stats_kernel<<<(NP2 + NP1) / 4, 256, 0, stream>>>(in1, in2, meanArr, invstdArr);
        corr_fp32<<<grid, 256, 0, stream>>>(in2, in1, meanArr, invstdArr, out);
    }
}

// Round 5
// 49.396 us; speedup vs baseline: 15.3442x; 1.0379x over previous
//
#include <hip/hip_runtime.h>

typedef float f32x4 __attribute__((ext_vector_type(4)));
typedef short s16x8 __attribute__((ext_vector_type(8)));
typedef unsigned int u32;
typedef u32 u32x2 __attribute__((ext_vector_type(2)));
typedef u32 u32x4 __attribute__((ext_vector_type(4)));

#define NB 8
#define HH 64
#define WW 32
#define CC 64
#define P2N 1680   // dense patches (input_2) = M
#define P1N 420    // strided patches (input_1) = N
#define OUTC 28
#define P1C 14
#define KF 1600
#define NP2 (NB*P2N)
#define NP1 (NB*P1N)
#define NELEM (NB*HH*WW*CC)   // 1048576
#define NPIX (NB*HH*WW)       // 16384

#define BM 128
#define BN 128

__device__ __forceinline__ u32 pack2_bf16(float x, float y) {
    u32 ux = __builtin_bit_cast(u32, x);
    u32 uy = __builtin_bit_cast(u32, y);
    ux = (ux + 0x7FFFu + ((ux >> 16) & 1u)) >> 16;
    uy = (uy + 0x7FFFu + ((uy >> 16) & 1u)) & 0xFFFF0000u;
    return (ux & 0xFFFFu) | uy;
}

__device__ __forceinline__ void glds16(const void* g, void* l) {
    __builtin_amdgcn_global_load_lds(
        (const __attribute__((address_space(1))) unsigned int*)g,
        (__attribute__((address_space(3))) unsigned int*)l, 16, 0, 0);
}

// ---- fused fp32->bf16 convert + per-pixel channel sums (16 lanes = 1 pixel) ----
__global__ __launch_bounds__(256) void cvt_pix(
    const float* __restrict__ in1, const float* __restrict__ in2,
    u32* __restrict__ o1, u32* __restrict__ o2,
    float* __restrict__ pS1, float* __restrict__ pQ1,
    float* __restrict__ pS2, float* __restrict__ pQ2)
{
    int i = blockIdx.x * 256 + threadIdx.x;   // [0, NELEM/4)
    f32x4 a = *(const f32x4*)(in1 + (size_t)i*4);
    f32x4 c = *(const f32x4*)(in2 + (size_t)i*4);
    u32x2 pa = { pack2_bf16(a.x, a.y), pack2_bf16(a.z, a.w) };
    u32x2 pc = { pack2_bf16(c.x, c.y), pack2_bf16(c.z, c.w) };
    ((u32x2*)o1)[i] = pa;
    ((u32x2*)o2)[i] = pc;
    float s1 = a.x + a.y + a.z + a.w;
    float q1 = a.x*a.x + a.y*a.y + a.z*a.z + a.w*a.w;
    float s2 = c.x + c.y + c.z + c.w;
    float q2 = c.x*c.x + c.y*c.y + c.z*c.z + c.w*c.w;
#pragma unroll
    for (int off = 1; off < 16; off <<= 1) {
        s1 += __shfl_xor(s1, off); q1 += __shfl_xor(q1, off);
        s2 += __shfl_xor(s2, off); q2 += __shfl_xor(q2, off);
    }
    if ((threadIdx.x & 15) == 0) {
        int p = i >> 4;
        pS1[p] = s1; pQ1[p] = q1; pS2[p] = s2; pQ2[p] = q2;
    }
}

// ---- per-patch mean / invstd from pixel partial sums ----
__global__ __launch_bounds__(256) void pstats(
    const float* __restrict__ pS1, const float* __restrict__ pQ1,
    const float* __restrict__ pS2, const float* __restrict__ pQ2,
    float* __restrict__ meanArr, float* __restrict__ invstdArr)
{
    int gid = blockIdx.x * 256 + threadIdx.x;
    if (gid >= NP2 + NP1) return;
    const float *pS, *pQ; int b, y, x;
    if (gid < NP2) {
        b = gid / P2N; int p = gid % P2N;
        y = p / OUTC; x = p % OUTC;
        pS = pS2; pQ = pQ2;
    } else {
        int g = gid - NP2;
        b = g / P1N; int p = g % P1N;
        y = (p / P1C) * 2; x = (p % P1C) * 2;
        pS = pS1; pQ = pQ1;
    }
    int base = (b*HH + y)*WW + x;
    float s = 0.f, q = 0.f;
#pragma unroll
    for (int dy = 0; dy < 5; ++dy)
#pragma unroll
        for (int dx = 0; dx < 5; ++dx) {
            int pp = base + dy*WW + dx;
            s += pS[pp]; q += pQ[pp];
        }
    float m = s * (1.f / KF);
    meanArr[gid] = m;
    invstdArr[gid] = rsqrtf(q * (1.f / KF) - m * m);
}

// ---- fallback exact-fp32 stats (only used if ws too small) ----
__global__ __launch_bounds__(256) void stats_kernel(
    const float* __restrict__ in1, const float* __restrict__ in2,
    float* __restrict__ meanArr, float* __restrict__ invstdArr)
{
    int gid = blockIdx.x * 4 + (threadIdx.x >> 6);
    int lane = threadIdx.x & 63;
    const float* src; int b, y, x;
    if (gid < NP2) {
        b = gid / P2N; int p = gid % P2N;
        y = p / OUTC; x = p % OUTC;
        src = in2;
    } else {
        int g = gid - NP2;
        b = g / P1N; int p = g % P1N;
        y = (p / P1C) * 2; x = (p % P1C) * 2;
        src = in1;
    }
    const float* base = src + (((b*HH + y)*WW + x)*CC) + lane;
    float s = 0.f, s2 = 0.f;
#pragma unroll
    for (int i = 0; i < 25; ++i) {
        int dy = i / 5, dx = i % 5;
        float v = base[(dy*WW + dx)*CC];
        s += v; s2 += v * v;
    }
#pragma unroll
    for (int off = 32; off; off >>= 1) {
        s  += __shfl_xor(s, off);
        s2 += __shfl_xor(s2, off);
    }
    if (lane == 0) {
        float m = s * (1.f / KF);
        float var = s2 * (1.f / KF) - m * m;
        meanArr[gid] = m;
        invstdArr[gid] = rsqrtf(var);
    }
}

// ============ bf16 MFMA correlation GEMM, global_load_lds staging ============
// 128x128 block, 4 waves (2x2) of 64x64. Double-buffered LDS A0|B0|A1|B1.
// Staging: global_load_lds width=16, LINEAR LDS dest (lane*16) with the XOR
// swizzle applied to the global SOURCE column (c16 ^ (row&7)); ds_read side
// applies the same XOR (both-sides-or-neither, m173/m201 pattern).
// One vmcnt(0)+barrier per chunk; stage(k+1) issued before the MFMA cluster.
__global__ __launch_bounds__(256) void corr_mfma_bf16(
    const short* __restrict__ aH, const short* __restrict__ bH,
    const float* __restrict__ meanArr, const float* __restrict__ invstdArr,
    float* __restrict__ out)
{
    __shared__ __align__(16) short lds[2*(BM+BN)*64];   // 64 KB
    char* Lc = (char*)lds;

    const int b  = blockIdx.z;
    const int m0 = blockIdx.y * BM;
    const int n0 = blockIdx.x * BN;
    const int t  = threadIdx.x;
    const int lane = t & 63;
    const int wid  = t >> 6;
    const int wm = wid >> 1, wn = wid & 1;      // 2x2 waves -> 64x64 each
    const int fr = lane & 15, fh = lane >> 4;

    // staging geometry: thread t -> row rsub (+32q), 16B unit c16; LDS dest is
    // linear lane*16 (= rsub*128 + c16*16), so swizzle goes on the SOURCE col.
    const int rsub = t >> 3;           // 0..31
    const int c16  = t & 7;            // 0..7
    const int csw  = (c16 ^ (rsub & 7)) * 8;   // pre-swizzled source column (elems)

    int aIdxS[4], bIdxS[4];            // per-lane global element offsets
#pragma unroll
    for (int q = 0; q < 4; ++q) {
        int ma = m0 + rsub + 32*q; if (ma > P2N-1) ma = P2N-1;
        int y = ma / OUTC, x = ma % OUTC;
        aIdxS[q] = ((b*HH + y)*WW + x)*CC + csw;
        int nb = n0 + rsub + 32*q; if (nb > P1N-1) nb = P1N-1;
        int yy = (nb / P1C)*2, xx = (nb % P1C)*2;
        bIdxS[q] = ((b*HH + yy)*WW + xx)*CC + csw;
    }

    // MFMA-side LDS read bases (XOR on read matches source pre-swizzle)
    const int swz = (fr & 7) << 4;
    const int rA0 = (wm*64+fr)*128 + ((fh*16) ^ swz);
    const int rA1 = (wm*64+fr)*128 + ((64 + fh*16) ^ swz);
    const int rB0 = 16384 + (wn*64+fr)*128 + ((fh*16) ^ swz);
    const int rB1 = 16384 + (wn*64+fr)*128 + ((64 + fh*16) ^ swz);

    f32x4 acc[4][4];
#pragma unroll
    for (int i = 0; i < 4; ++i)
#pragma unroll
        for (int j = 0; j < 4; ++j) acc[i][j] = (f32x4){0.f,0.f,0.f,0.f};

    const int wslot = wid * 1024;      // wave's linear 1KB slot inside a q-group

#define GOFF(c) ((((c)/5)*WW + ((c)%5))*CC)
#define STAGE(C, P) { _Pragma("unroll") for (int q = 0; q < 4; ++q) { \
        glds16(aH + aIdxS[q] + GOFF(C), Lc + (P)*32768 +         q*4096 + wslot); \
        glds16(bH + bIdxS[q] + GOFF(C), Lc + (P)*32768 + 16384 + q*4096 + wslot); } }

    // prologue: stage chunk 0 -> buf 0
    STAGE(0, 0);

#pragma unroll
    for (int kk = 0; kk < 25; ++kk) {
        const int P = kk & 1;
        __syncthreads();   // vmcnt(0)+barrier: buf[P] fully landed; buf[1-P] readers done

        // issue next chunk's staging into buf[1-P] (in flight across the MFMAs)
        if (kk + 1 < 25) {
            if (P == 0) STAGE(kk + 1, 1) else STAGE(kk + 1, 0)
        }

        // MFMA on buf[P]
        __builtin_amdgcn_s_setprio(1);
#pragma unroll
        for (int s = 0; s < 2; ++s) {
            const int rAs = s ? rA1 : rA0;
            const int rBs = s ? rB1 : rB0;
            s16x8 af[4], bfr[4];
#pragma unroll
            for (int i = 0; i < 4; ++i)
                af[i] = *(const s16x8*)(Lc + rAs + i*2048 + P*32768);
#pragma unroll
            for (int j = 0; j < 4; ++j)
                bfr[j] = *(const s16x8*)(Lc + rBs + j*2048 + P*32768);
#pragma unroll
            for (int i = 0; i < 4; ++i)
#pragma unroll
                for (int j = 0; j < 4; ++j)
                    acc[i][j] = __builtin_amdgcn_mfma_f32_16x16x32_bf16(af[i], bfr[j], acc[i][j], 0, 0, 0);
        }
        __builtin_amdgcn_s_setprio(0);
    }

    // ---- epilogue: (dot - K*m2*m1) * is2 * is1 ----
    float m1v[4], is1v[4];
#pragma unroll
    for (int j = 0; j < 4; ++j) {
        int n = n0 + wn*64 + j*16 + fr;
        int nc = n > P1N-1 ? P1N-1 : n;
        m1v[j]  = meanArr[NP2 + b*P1N + nc];
        is1v[j] = invstdArr[NP2 + b*P1N + nc];
    }
#pragma unroll
    for (int i = 0; i < 4; ++i) {
#pragma unroll
        for (int r = 0; r < 4; ++r) {
            int m = m0 + wm*64 + i*16 + fh*4 + r;
            if (m >= P2N) continue;
            float m2  = meanArr[b*P2N + m];
            float is2 = invstdArr[b*P2N + m];
            size_t obase = ((size_t)b*P2N + m) * P1N;
#pragma unroll
            for (int j = 0; j < 4; ++j) {
                int n = n0 + wn*64 + j*16 + fr;
                if (n >= P1N) continue;
                out[obase + n] = (acc[i][j][r] - (float)KF * m2 * m1v[j]) * is2 * is1v[j];
            }
        }
    }
#undef GOFF
#undef STAGE
}

// ---- fallback fp32 corr (used only if ws too small) ----
__global__ __launch_bounds__(256) void corr_fp32(
    const float* __restrict__ aF, const float* __restrict__ bF,
    const float* __restrict__ meanArr, const float* __restrict__ invstdArr,
    float* __restrict__ out)
{
    __shared__ short As[2][BM*64];
    __shared__ short Bs[2][BN*64];
    const int b  = blockIdx.z;
    const int m0 = blockIdx.y * BM;
    const int n0 = blockIdx.x * BN;
    const int t  = threadIdx.x;
    const int lane = t & 63;
    const int wid  = t >> 6;
    const int wm = wid >> 1, wn = wid & 1;
    const int fr = lane & 15, fh = lane >> 4;
    const int rsub = t >> 3, c16 = t & 7;
    const int colElem = c16 * 8;
    const int swz = (rsub & 7) << 4;
    const int wByte = rsub*128 + c16*16;

    int aOff[4], bOff[4];
#pragma unroll
    for (int q = 0; q < 4; ++q) {
        int ma = m0 + rsub + 32*q; if (ma > P2N-1) ma = P2N-1;
        int y = ma / OUTC, x = ma % OUTC;
        aOff[q] = ((b*HH + y)*WW + x)*CC;
        int nb = n0 + rsub + 32*q; if (nb > P1N-1) nb = P1N-1;
        int yy = (nb / P1C)*2, xx = (nb % P1C)*2;
        bOff[q] = ((b*HH + yy)*WW + xx)*CC;
    }
    f32x4 acc[4][4];
#pragma unroll
    for (int i = 0; i < 4; ++i)
#pragma unroll
        for (int j = 0; j < 4; ++j) acc[i][j] = (f32x4){0.f,0.f,0.f,0.f};

    f32x4 avF[4][2], bvF[4][2];
#pragma unroll
    for (int q = 0; q < 4; ++q) {
        avF[q][0] = *(const f32x4*)(aF + aOff[q] + colElem);
        avF[q][1] = *(const f32x4*)(aF + aOff[q] + colElem + 4);
        bvF[q][0] = *(const f32x4*)(bF + bOff[q] + colElem);
        bvF[q][1] = *(const f32x4*)(bF + bOff[q] + colElem + 4);
    }
    {
        char* AsB = (char*)As[0]; char* BsB = (char*)Bs[0];
#pragma unroll
        for (int q = 0; q < 4; ++q) {
            u32x4 va = { pack2_bf16(avF[q][0].x, avF[q][0].y), pack2_bf16(avF[q][0].z, avF[q][0].w),
                         pack2_bf16(avF[q][1].x, avF[q][1].y), pack2_bf16(avF[q][1].z, avF[q][1].w) };
            u32x4 vb = { pack2_bf16(bvF[q][0].x, bvF[q][0].y), pack2_bf16(bvF[q][0].z, bvF[q][0].w),
                         pack2_bf16(bvF[q][1].x, bvF[q][1].y), pack2_bf16(bvF[q][1].z, bvF[q][1].w) };
            *(u32x4*)(AsB + ((wByte + q*4096) ^ swz)) = va;
            *(u32x4*)(BsB + ((wByte + q*4096) ^ swz)) = vb;
        }
    }
    for (int kk = 0; kk < 25; ++kk) {
        __syncthreads();
        if (kk < 24) {
            int kn = kk + 1;
            int goff = ((kn/5)*WW + (kn%5))*CC + colElem;
#pragma unroll
            for (int q = 0; q < 4; ++q) {
                avF[q][0] = *(const f32x4*)(aF + aOff[q] + goff);
                avF[q][1] = *(const f32x4*)(aF + aOff[q] + goff + 4);
                bvF[q][0] = *(const f32x4*)(bF + bOff[q] + goff);
                bvF[q][1] = *(const f32x4*)(bF + bOff[q] + goff + 4);
            }
        }
        {
            const char* AsB = (const char*)As[kk & 1];
            const char* BsB = (const char*)Bs[kk & 1];
#pragma unroll
            for (int step = 0; step < 2; ++step) {
                s16x8 af[4], bfr[4];
#pragma unroll
                for (int i = 0; i < 4; ++i) {
                    int row = wm*64 + i*16 + fr;
                    af[i] = *(const s16x8*)(AsB + ((row*128 + step*64 + fh*16) ^ ((fr & 7) << 4)));
                }
#pragma unroll
                for (int j = 0; j < 4; ++j) {
                    int row = wn*64 + j*16 + fr;
                    bfr[j] = *(const s16x8*)(BsB + ((row*128 + step*64 + fh*16) ^ ((fr & 7) << 4)));
                }
#pragma unroll
                for (int i = 0; i < 4; ++i)
#pragma unroll
                    for (int j = 0; j < 4; ++j)
                        acc[i][j] = __builtin_amdgcn_mfma_f32_16x16x32_bf16(af[i], bfr[j], acc[i][j], 0, 0, 0);
            }
        }
        if (kk < 24) {
            char* AsB = (char*)As[(kk + 1) & 1];
            char* BsB = (char*)Bs[(kk + 1) & 1];
#pragma unroll
            for (int q = 0; q < 4; ++q) {
                u32x4 va = { pack2_bf16(avF[q][0].x, avF[q][0].y), pack2_bf16(avF[q][0].z, avF[q][0].w),
                             pack2_bf16(avF[q][1].x, avF[q][1].y), pack2_bf16(avF[q][1].z, avF[q][1].w) };
                u32x4 vb = { pack2_bf16(bvF[q][0].x, bvF[q][0].y), pack2_bf16(bvF[q][0].z, bvF[q][0].w),
                             pack2_bf16(bvF[q][1].x, bvF[q][1].y), pack2_bf16(bvF[q][1].z, bvF[q][1].w) };
                *(u32x4*)(AsB + ((wByte + q*4096) ^ swz)) = va;
                *(u32x4*)(BsB + ((wByte + q*4096) ^ swz)) = vb;
            }
        }
    }
    float m1v[4], is1v[4];
#pragma unroll
    for (int j = 0; j < 4; ++j) {
        int n = n0 + wn*64 + j*16 + fr;
        int nc = n > P1N-1 ? P1N-1 : n;
        m1v[j]  = meanArr[NP2 + b*P1N + nc];
        is1v[j] = invstdArr[NP2 + b*P1N + nc];
    }
#pragma unroll
    for (int i = 0; i < 4; ++i) {
#pragma unroll
        for (int r = 0; r < 4; ++r) {
            int m = m0 + wm*64 + i*16 + fh*4 + r;
            if (m >= P2N) continue;
            float m2  = meanArr[b*P2N + m];
            float is2 = invstdArr[b*P2N + m];
            size_t obase = ((size_t)b*P2N + m) * P1N;
#pragma unroll
            for (int j = 0; j < 4; ++j) {
                int n = n0 + wn*64 + j*16 + fr;
                if (n >= P1N) continue;
                out[obase + n] = (acc[i][j][r] - (float)KF * m2 * m1v[j]) * is2 * is1v[j];
            }
        }
    }
}

extern "C" void kernel_launch(void* const* d_in, const int* in_sizes, int n_in,
                              void* d_out, int out_size, void* d_ws, size_t ws_size,
                              hipStream_t stream) {
    const float* in1 = (const float*)d_in[0];   // strided patches -> N side
    const float* in2 = (const float*)d_in[1];   // dense patches   -> M side
    float* out = (float*)d_out;

    float* meanArr   = (float*)d_ws;
    float* invstdArr = meanArr + (NP2 + NP1);
    float* pS1 = invstdArr + (NP2 + NP1);
    float* pQ1 = pS1 + NPIX;
    float* pS2 = pQ1 + NPIX;
    float* pQ2 = pS2 + NPIX;
    short* b1 = (short*)(pQ2 + NPIX);           // bf16 input_1
    short* b2 = b1 + NELEM;                     // bf16 input_2
    size_t need = (size_t)((char*)(b2 + NELEM) - (char*)d_ws);
    bool useBf16 = (ws_size >= need);

    dim3 grid((P1N + BN - 1) / BN, (P2N + BM - 1) / BM, NB);   // 4 x 14 x 8

    if (useBf16) {
        cvt_pix<<<NELEM/4/256, 256, 0, stream>>>(in1, in2, (u32*)b1, (u32*)b2,
                                                 pS1, pQ1, pS2, pQ2);
        pstats<<<(NP2 + NP1 + 255)/256, 256, 0, stream>>>(pS1, pQ1, pS2, pQ2,
                                                          meanArr, invstdArr);
        corr_mfma_bf16<<<grid, 256, 0, stream>>>(b2, b1, meanArr, invstdArr, out);
    } else {
        stats_kernel<<<(NP2 + NP1) / 4, 256, 0, stream>>>(in1, in2, meanArr, invstdArr);
        corr_fp32<<<grid, 256, 0, stream>>>(in2, in1, meanArr, invstdArr, out);
    }
}